// Round 15
// baseline (82.794 us; speedup 1.0000x reference)
//
#include <hip/hip_runtime.h>
#include <hip/hip_bf16.h>
#include <stdint.h>

#define B_ 8
#define L_ 1024
#define DM 512
#define H_ 8
#define HD 64
#define N3 1536
#define M_T (B_*L_)        // 8192
#define LOG2E 1.44269504f

typedef __attribute__((ext_vector_type(8))) short short8;    // 8 x bf16 (4 VGPRs)
typedef __attribute__((ext_vector_type(4))) float f32x4;
typedef __attribute__((ext_vector_type(4))) float float4_t;
typedef __attribute__((ext_vector_type(4))) unsigned short ushort4_t;
typedef __attribute__((ext_vector_type(2))) unsigned int u32x2;

#define MFMA16(a,b,c) __builtin_amdgcn_mfma_f32_16x16x32_bf16((a),(b),(c),0,0,0)

// global -> LDS 16B DMA (wave-uniform LDS base + lane*16; per-lane global src)
#define GLL(gp, lp) __builtin_amdgcn_global_load_lds( \
    (const __attribute__((address_space(1))) void*)(gp), \
    (__attribute__((address_space(3))) void*)(lp), 16, 0, 0)

__device__ __forceinline__ short f2bf(float f){            // manual RNE (prep)
  union { float f; unsigned u; } v; v.f = f;
  unsigned r = v.u + 0x7fffu + ((v.u >> 16) & 1u);
  return (short)(r >> 16);
}

__device__ __forceinline__ short f2bf_fast(float f){       // native cvt (hot paths)
  __hip_bfloat16 h = __float2bfloat16(f);
  short s; __builtin_memcpy(&s, &h, 2); return s;
}

// ---------------- fused prep: mask prescale/tile | both weight transposes ----------------
// blocks [0,1024): maskP; [1024,1280): transposes   (x->bf16 cvt folded into GEMM1)
__global__ __launch_bounds__(256) void k_prep(
    const float* __restrict__ mask, float* __restrict__ maskP,
    const float* __restrict__ W0, short* __restrict__ WT0,
    const float* __restrict__ W1, short* __restrict__ WT1)
{
  __shared__ float t[64][65];
  const int blk = blockIdx.x, tid = threadIdx.x;

  if (blk < 1024){                                  // ---- mask -> prescaled transposed-fragment tiles
    // maskP flat = qg*16384 + kvt*1024 + lane*16 + nf*4 + j
    //   value = mask[qg*16 + li][kvt*64 + nf*16 + lg*4 + j] * LOG2E - 17.3123405
    int gid = blk*256 + tid;
    int nf  = gid & 3;
    int lane= (gid>>2) & 63;
    int kvt = (gid>>8) & 15;
    int qg  = gid>>12;
    int li = lane & 15, lg = lane >> 4;
    int row = qg*16 + li;
    int col = kvt*64 + nf*16 + lg*4;
    float4_t m = *(const float4_t*)(mask + (size_t)row*1024 + col);
    float4_t o;
    #pragma unroll
    for (int j=0;j<4;++j) o[j] = fmaf(m[j], LOG2E, -17.3123405f);
    ((float4_t*)maskP)[gid] = o;
    return;
  }
  // ---- W [512][N] fp32 -> WT [N][512] bf16 (both weights)
  int idx = blk - 1024;                             // [0,256)
  int bx = idx & 31, by = idx >> 5;
  const float* W; short* WT; int N, n0;
  if (bx < 24){ W = W0; WT = WT0; N = N3; n0 = bx*64; }
  else        { W = W1; WT = WT1; N = DM; n0 = (bx-24)*64; }
  int k0 = by*64;
  int r = tid >> 4, c4 = (tid & 15) * 4;
  #pragma unroll
  for (int it=0; it<4; ++it){
    int rr = r + it*16;
    float4_t v = *(const float4_t*)(W + (size_t)(k0+rr)*N + n0 + c4);
    t[rr][c4+0]=v[0]; t[rr][c4+1]=v[1]; t[rr][c4+2]=v[2]; t[rr][c4+3]=v[3];
  }
  __syncthreads();
  #pragma unroll
  for (int it=0; it<4; ++it){
    int n = r + it*16;
    ushort4_t o;
    o[0]=(unsigned short)f2bf(t[c4+0][n]);
    o[1]=(unsigned short)f2bf(t[c4+1][n]);
    o[2]=(unsigned short)f2bf(t[c4+2][n]);
    o[3]=(unsigned short)f2bf(t[c4+3][n]);
    *(ushort4_t*)(WT + (size_t)(n0+n)*DM + k0 + c4) = o;
  }
}

// ---------------- GEMM1: 128x192 tiles, A reg-staged from fp32 x (fused cvt), B via gload_lds ----------------
// grid 1D 512: id = (x&7) + 8*y + 64*(x>>3)  ->  all 8 y-blocks of an A-panel share one XCD (id&7)
__global__ __launch_bounds__(256) void k_gemm_qkv(
    const float* __restrict__ X, const short* __restrict__ Bt,
    const float* __restrict__ bias,
    short* __restrict__ Qo, short* __restrict__ Ko, short* __restrict__ VTo)
{
  __shared__ __align__(16) short As[2][128*32];
  __shared__ __align__(16) short Bs[2][192*32];
  const int id  = blockIdx.x;
  const int xlo = id & 7, yy = (id>>3) & 7, xhi = id >> 6;
  const int m0  = (xhi*8 + xlo)*128, n0 = yy*192;
  const int tid = threadIdx.x;
  const int w = tid>>6, lane = tid&63, li = lane&15, lg = lane>>4;
  const int wr = (w>>1)*64, wc = (w&1)*96;

  // staging: chunk c -> lds row c>>2, lds slot c&3; global slot = (c&3)^(row&3)
  const int r0 = tid>>2;
  const int s0 = (tid&3) ^ (r0&3);       // rows +64/+128: row&3 identical -> same s0
  const int swz = li&3;                  // read-side xor

  #define G1_STAGEB(buf, kt) do { \
    GLL(Bt + (size_t)(n0+r0    )*DM + (kt)*32 + s0*8, &Bs[buf][tid*8]); \
    GLL(Bt + (size_t)(n0+r0+64 )*DM + (kt)*32 + s0*8, &Bs[buf][(tid+256)*8]); \
    GLL(Bt + (size_t)(n0+r0+128)*DM + (kt)*32 + s0*8, &Bs[buf][(tid+512)*8]); \
  } while(0)

  // A: load 8 fp32 per chunk (2 chunks) from x; cvt; ds_write b128 to same LDS image the GLL used
  float4_t xa0, xa1, xa2, xa3;
  auto LOADA = [&](int kt){
    const float* b0 = X + (size_t)(m0+r0   )*DM + kt*32 + s0*8;
    const float* b1 = X + (size_t)(m0+r0+64)*DM + kt*32 + s0*8;
    xa0 = *(const float4_t*)b0; xa1 = *(const float4_t*)(b0+4);
    xa2 = *(const float4_t*)b1; xa3 = *(const float4_t*)(b1+4);
  };
  auto WRITEA = [&](int buf){
    short8 w0, w1;
    #pragma unroll
    for (int j=0;j<4;++j){
      w0[j]   = f2bf_fast(xa0[j]);  w0[4+j] = f2bf_fast(xa1[j]);
      w1[j]   = f2bf_fast(xa2[j]);  w1[4+j] = f2bf_fast(xa3[j]);
    }
    *(short8*)&As[buf][tid*8]       = w0;
    *(short8*)&As[buf][(tid+256)*8] = w1;
  };

  const f32x4 fz = {0.f,0.f,0.f,0.f};
  f32x4 acc[4][6];
  #pragma unroll
  for (int i=0;i<4;++i)
    #pragma unroll
    for (int j=0;j<6;++j) acc[i][j] = fz;

  LOADA(0);
  G1_STAGEB(0, 0);
  WRITEA(0);
  __syncthreads();                      // drains B-DMA, A-writes visible

  for (int kt=0; kt<16; ++kt){
    const short* as = As[kt&1]; const short* bs = Bs[kt&1];
    if (kt < 15){
      LOADA(kt+1);                      // latency covered by compute below
      G1_STAGEB((kt&1)^1, kt+1);
    }
    short8 bfr[6];
    #pragma unroll
    for (int nf=0;nf<6;++nf)
      bfr[nf] = *(const short8*)&bs[(wc + nf*16 + li)*32 + (lg^swz)*8];
    __builtin_amdgcn_s_setprio(1);
    #pragma unroll
    for (int mf=0;mf<4;++mf){
      short8 af = *(const short8*)&as[(wr + mf*16 + li)*32 + (lg^swz)*8];
      #pragma unroll
      for (int nf=0;nf<6;++nf)
        acc[mf][nf] = MFMA16(af, bfr[nf], acc[mf][nf]);
    }
    __builtin_amdgcn_s_setprio(0);
    if (kt < 15) WRITEA((kt&1)^1);      // buf^1 last read in kt-1 (pre-barrier) -> safe
    __syncthreads();
  }

  // epilogue: col n -> head h = n/192; within: [0,64)=Q, [64,128)=K, [128,192)=V(transposed store)
  #pragma unroll
  for (int nf=0;nf<6;++nf){
    int n = n0 + wc + nf*16 + li;
    float bv = bias[n];
    unsigned h  = (unsigned)n / 192u;
    unsigned wn = (unsigned)n % 192u;
    unsigned typ = wn >> 6, d = wn & 63u;
    #pragma unroll
    for (int mf=0;mf<4;++mf){
      #pragma unroll
      for (int j=0;j<4;++j){
        int m  = m0 + wr + mf*16 + lg*4 + j;
        int b  = m >> 10, lp = m & 1023;
        size_t bh = (size_t)(b*8 + (int)h);
        float vf = acc[mf][nf][j] + bv;
        if (typ == 0)      Qo [(bh<<16) + ((size_t)lp<<6)  + d]  = f2bf_fast(vf * 0.18033688f); // 0.125*log2e
        else if (typ == 1) Ko [(bh<<16) + ((size_t)lp<<6)  + d]  = f2bf_fast(vf);
        else               VTo[(bh<<16) + ((size_t)d<<10)  + lp] = f2bf_fast(vf);
      }
    }
  }
  #undef G1_STAGEB
}

// ---------------- flash attention (proven): gload_lds K/V + XOR swizzle + XCD-local, P via LDS ----------------
__global__ __launch_bounds__(256, 2) void k_attn(
    const short* __restrict__ Q, const short* __restrict__ Kb,
    const short* __restrict__ VT, const float* __restrict__ maskP,
    short* __restrict__ O2)
{
  __shared__ __align__(16) short Ks[2][64*64];   // linear [kv][d], source-swizzled
  __shared__ __align__(16) short Vs[2][64*64];   // linear [d][kv], source-swizzled
  __shared__ __align__(16) short Ps[4][32*72];

  // XCD-local decode: all 8 q-blocks of a bh land on one XCD (hw xcd = id & 7)
  const int id  = blockIdx.x;
  const int bh  = (id & 7)*8 + ((id >> 3) & 7);
  const int q0  = (id >> 6) * 128;

  const int tid = threadIdx.x, w = tid>>6, lane = tid&63, li = lane&15, lg = lane>>4;
  const int qw = q0 + w*32;

  const short* Qp = Q  + ((size_t)bh<<16);
  const short* Kp = Kb + ((size_t)bh<<16);
  const short* Vp = VT + ((size_t)bh<<16);

  // staging chunk geometry: chunk c covers (row=c>>3, lds slot=c&7); global slot = lds slot ^ (row&7)
  const int arow0 = tid>>3;
  const int ags0  = (tid&7) ^ (arow0&7);         // chunk1: row+32 -> same (row&7), same gslot

  #define ATTN_STAGE(buf, nx) do { \
    GLL(Kp + ((size_t)((nx)+arow0   )<<6) + ags0*8, &Ks[buf][tid*8]); \
    GLL(Kp + ((size_t)((nx)+arow0+32)<<6) + ags0*8, &Ks[buf][(tid+256)*8]); \
    GLL(Vp + ((size_t)(arow0   )<<10) + (nx) + ags0*8, &Vs[buf][tid*8]); \
    GLL(Vp + ((size_t)(arow0+32)<<10) + (nx) + ags0*8, &Vs[buf][(tid+256)*8]); \
  } while(0)

  // Q as B-operand (col=q=li, k=d), two m-blocks; Q pre-scaled in GEMM1
  short8 qf[2][2];
  #pragma unroll
  for (int mb=0;mb<2;++mb)
    #pragma unroll
    for (int t=0;t<2;++t)
      qf[mb][t] = *(const short8*)(Qp + ((size_t)(qw+mb*16+li)<<6) + t*32 + lg*8);

  short8 ones8;
  #pragma unroll
  for (int e=0;e<8;++e) ones8[e] = (short)0x3f80;   // bf16 1.0

  const f32x4 fz = {0.f,0.f,0.f,0.f};
  f32x4 o[2][4], osum[2];
  #pragma unroll
  for (int mb=0;mb<2;++mb){
    osum[mb] = fz;
    #pragma unroll
    for (int df=0;df<4;++df) o[mb][df] = fz;
  }

  // mask (transposed-fragment, prescaled); register prefetch one tile ahead
  const float* mpb[2];
  #pragma unroll
  for (int mb=0;mb<2;++mb)
    mpb[mb] = maskP + ((size_t)((qw>>4)+mb)<<14) + lane*16;
  f32x4 mnx[2][4];
  #pragma unroll
  for (int mb=0;mb<2;++mb)
    #pragma unroll
    for (int nf=0;nf<4;++nf)
      mnx[mb][nf] = *(const float4_t*)(mpb[mb] + nf*4);

  ATTN_STAGE(0, 0);
  __syncthreads();     // drains vmcnt -> tile 0 staged

  const int sw = li & 7;
  short* pw = Ps[w];

  for (int kvt=0; kvt<16; ++kvt){
    const short* ks = Ks[kvt&1];
    const short* vs = Vs[kvt&1];
    if (kvt < 15) ATTN_STAGE((kvt&1)^1, (kvt+1)*64);

    // swapped QK^T: S^T[kv][q] tiles; C-init = prefetched mask regs
    f32x4 s[2][4];
    __builtin_amdgcn_s_setprio(1);
    #pragma unroll
    for (int nf=0;nf<4;++nf){
      short8 kf0 = *(const short8*)&ks[(nf*16+li)*64 + ((  lg)^sw)*8];
      short8 kf1 = *(const short8*)&ks[(nf*16+li)*64 + ((4|lg)^sw)*8];
      #pragma unroll
      for (int mb=0;mb<2;++mb){
        s[mb][nf] = MFMA16(kf0, qf[mb][0], mnx[mb][nf]);
        s[mb][nf] = MFMA16(kf1, qf[mb][1], s[mb][nf]);
      }
    }
    __builtin_amdgcn_s_setprio(0);

    // prefetch next tile's mask (consumed next iteration)
    if (kvt < 15){
      #pragma unroll
      for (int mb=0;mb<2;++mb)
        #pragma unroll
        for (int nf=0;nf<4;++nf)
          mnx[mb][nf] = *(const float4_t*)(mpb[mb] + (kvt+1)*1024 + nf*4);
    }

    // p = exp2(s) -> packed bf16 pairs -> Ps[q][kv] (b64 writes)
    #pragma unroll
    for (int mb=0;mb<2;++mb){
      #pragma unroll
      for (int nf=0;nf<4;++nf){
        float e0 = __builtin_amdgcn_exp2f(s[mb][nf][0]);
        float e1 = __builtin_amdgcn_exp2f(s[mb][nf][1]);
        float e2 = __builtin_amdgcn_exp2f(s[mb][nf][2]);
        float e3 = __builtin_amdgcn_exp2f(s[mb][nf][3]);
        unsigned p01, p23;
        asm("v_cvt_pk_bf16_f32 %0, %1, %2" : "=v"(p01) : "v"(e0), "v"(e1));
        asm("v_cvt_pk_bf16_f32 %0, %1, %2" : "=v"(p23) : "v"(e2), "v"(e3));
        u32x2 pv; pv[0]=p01; pv[1]=p23;
        *(u32x2*)&pw[(mb*16+li)*72 + nf*16 + lg*4] = pv;
      }
    }

    // PV: O[32q x 64d] += P @ V ; V-frags shared across both m-blocks
    __builtin_amdgcn_s_setprio(1);
    #pragma unroll
    for (int t=0;t<2;++t){
      short8 pf0 = *(const short8*)&pw[(   li)*72 + t*32 + lg*8];
      short8 pf1 = *(const short8*)&pw[(16+li)*72 + t*32 + lg*8];
      osum[0] = MFMA16(pf0, ones8, osum[0]);
      osum[1] = MFMA16(pf1, ones8, osum[1]);
      #pragma unroll
      for (int df=0;df<4;++df){
        short8 vf = *(const short8*)&vs[(df*16+li)*64 + (((t<<2)|lg)^sw)*8];
        o[0][df] = MFMA16(pf0, vf, o[0][df]);
        o[1][df] = MFMA16(pf1, vf, o[1][df]);
      }
    }
    __builtin_amdgcn_s_setprio(0);

    __syncthreads();   // buf[cur] reads done + buf[cur^1] DMA drained (vmcnt 0 at barrier)
  }
  #undef ATTN_STAGE

  // epilogue: O2[b, l, h*64+d] bf16
  int b = bh >> 3, h = bh & 7;
  #pragma unroll
  for (int mb=0;mb<2;++mb){
    float rl[4];
    #pragma unroll
    for (int j=0;j<4;++j) rl[j] = 1.0f / osum[mb][j];
    #pragma unroll
    for (int df=0;df<4;++df)
      #pragma unroll
      for (int j=0;j<4;++j){
        int m   = b*1024 + qw + mb*16 + lg*4 + j;
        int col = h*64 + df*16 + li;
        O2[(size_t)m*512 + col] = f2bf_fast(o[mb][df][j] * rl[j]);
      }
  }
}

// ---------------- GEMM2: 64x128 tiles, XCD-local A-panels, gload_lds + XOR-4 swizzle ----------------
// grid 1D 512: id = (x&7) + 8*y + 32*(x>>3) ; x in [0,128), y in [0,4)
__global__ __launch_bounds__(256) void k_gemm_out(
    const short* __restrict__ A, const short* __restrict__ Bt,
    const float* __restrict__ bias, float* __restrict__ out)
{
  __shared__ __align__(16) short As[2][64*32];
  __shared__ __align__(16) short Bs[2][128*32];
  const int id  = blockIdx.x;
  const int xlo = id & 7, yy = (id>>3) & 3, xhi = id >> 5;
  const int m0  = (xhi*8 + xlo)*64, n0 = yy*128;
  const int tid = threadIdx.x;
  const int w = tid>>6, lane = tid&63, li = lane&15, lg = lane>>4;
  const int wc = w*32;                  // wave covers cols [wc, wc+32), all 64 rows

  const int r0 = tid>>2;
  const int s0 = (tid&3) ^ (r0&3);
  const int swz = li&3;
  const int ra = tid>>2;                // A: 64 rows x 4 slots = 256 chunks (1 GLL)

  #define G2_STAGE(buf, kt) do { \
    GLL(A  + (size_t)(m0+ra    )*DM + (kt)*32 + s0*8, &As[buf][tid*8]); \
    GLL(Bt + (size_t)(n0+r0    )*DM + (kt)*32 + s0*8, &Bs[buf][tid*8]); \
    GLL(Bt + (size_t)(n0+r0+64 )*DM + (kt)*32 + s0*8, &Bs[buf][(tid+256)*8]); \
  } while(0)

  const f32x4 fz = {0.f,0.f,0.f,0.f};
  f32x4 acc[4][2];
  #pragma unroll
  for (int i=0;i<4;++i)
    #pragma unroll
    for (int j=0;j<2;++j) acc[i][j] = fz;

  G2_STAGE(0, 0);
  __syncthreads();

  for (int kt=0; kt<16; ++kt){
    const short* as = As[kt&1]; const short* bs = Bs[kt&1];
    if (kt < 15) G2_STAGE((kt&1)^1, kt+1);
    short8 bfr[2];
    #pragma unroll
    for (int nf=0;nf<2;++nf)
      bfr[nf] = *(const short8*)&bs[(wc + nf*16 + li)*32 + (lg^swz)*8];
    __builtin_amdgcn_s_setprio(1);
    #pragma unroll
    for (int mf=0;mf<4;++mf){
      short8 af = *(const short8*)&as[(mf*16 + li)*32 + (lg^swz)*8];
      #pragma unroll
      for (int nf=0;nf<2;++nf)
        acc[mf][nf] = MFMA16(af, bfr[nf], acc[mf][nf]);
    }
    __builtin_amdgcn_s_setprio(0);
    __syncthreads();
  }

  #pragma unroll
  for (int nf=0;nf<2;++nf){
    int n = n0 + wc + nf*16 + li;
    float bv = bias[n];
    #pragma unroll
    for (int mf=0;mf<4;++mf){
      #pragma unroll
      for (int j=0;j<4;++j){
        int m = m0 + mf*16 + lg*4 + j;
        out[(size_t)m*DM + n] = acc[mf][nf][j] + bv;
      }
    }
  }
  #undef G2_STAGE
}

extern "C" void kernel_launch(void* const* d_in, const int* in_sizes, int n_in,
                              void* d_out, int out_size, void* d_ws, size_t ws_size,
                              hipStream_t stream)
{
  (void)in_sizes; (void)n_in; (void)out_size; (void)ws_size;
  const float* x    = (const float*)d_in[0];
  const float* mask = (const float*)d_in[1];
  const float* Wqkv = (const float*)d_in[2];
  const float* bqkv = (const float*)d_in[3];
  const float* Wo   = (const float*)d_in[4];
  const float* bo   = (const float*)d_in[5];
  float* out = (float*)d_out;

  short* xb    = (short*)d_ws;                    // region kept for layout stability (unused)
  short* WqkvT = xb    + (size_t)M_T*DM;          // [1536,512] bf16
  short* WoT   = WqkvT + (size_t)N3*DM;           // [512,512]  bf16
  short* Qb    = WoT   + (size_t)DM*DM;           // [64][1024][64] bf16 (pre-scaled)
  short* Kbf   = Qb    + (size_t)64*1024*64;      // [64][1024][64] bf16
  short* VTb   = Kbf   + (size_t)64*1024*64;      // [64][64][1024] bf16 (V^T)
  short* O2    = VTb   + (size_t)64*1024*64;      // [8192,512] bf16
  float* maskP = (float*)(O2 + (size_t)M_T*DM);   // [1024,1024] fp32 prescaled tiles (ws ~268MB, fits)

  k_prep<<<1280, 256, 0, stream>>>(mask, maskP, Wqkv, WqkvT, Wo, WoT);
  k_gemm_qkv<<<512, 256, 0, stream>>>(x, WqkvT, bqkv, Qb, Kbf, VTb);
  k_attn    <<<512, 256, 0, stream>>>(Qb, Kbf, VTb, maskP, O2);
  k_gemm_out<<<512, 256, 0, stream>>>(O2, WoT, bo, out);
}

// Round 16
// 80.199 us; speedup vs baseline: 1.0324x; 1.0324x over previous
//
#include <hip/hip_runtime.h>
#include <hip/hip_bf16.h>
#include <stdint.h>

#define B_ 8
#define L_ 1024
#define DM 512
#define H_ 8
#define HD 64
#define N3 1536
#define M_T (B_*L_)        // 8192
#define LOG2E 1.44269504f

typedef __attribute__((ext_vector_type(8))) short short8;    // 8 x bf16 (4 VGPRs)
typedef __attribute__((ext_vector_type(4))) float f32x4;
typedef __attribute__((ext_vector_type(4))) float float4_t;
typedef __attribute__((ext_vector_type(4))) unsigned short ushort4_t;
typedef __attribute__((ext_vector_type(2))) unsigned int u32x2;

#define MFMA16(a,b,c) __builtin_amdgcn_mfma_f32_16x16x32_bf16((a),(b),(c),0,0,0)

// global -> LDS 16B DMA (wave-uniform LDS base + lane*16; per-lane global src)
#define GLL(gp, lp) __builtin_amdgcn_global_load_lds( \
    (const __attribute__((address_space(1))) void*)(gp), \
    (__attribute__((address_space(3))) void*)(lp), 16, 0, 0)

__device__ __forceinline__ short f2bf(float f){            // manual RNE (prep)
  union { float f; unsigned u; } v; v.f = f;
  unsigned r = v.u + 0x7fffu + ((v.u >> 16) & 1u);
  return (short)(r >> 16);
}

__device__ __forceinline__ short f2bf_fast(float f){       // native cvt (hot paths)
  __hip_bfloat16 h = __float2bfloat16(f);
  short s; __builtin_memcpy(&s, &h, 2); return s;
}

// ---------------- fused prep: x->bf16 | mask prescale/tile | both weight transposes ----------------
// blocks [0,2048): cvt; [2048,3072): maskP; [3072,3328): transposes
__global__ __launch_bounds__(256) void k_prep(
    const float* __restrict__ x,  short* __restrict__ xb,
    const float* __restrict__ mask, float* __restrict__ maskP,
    const float* __restrict__ W0, short* __restrict__ WT0,
    const float* __restrict__ W1, short* __restrict__ WT1)
{
  __shared__ float t[64][65];
  const int blk = blockIdx.x, tid = threadIdx.x;

  if (blk < 2048){                                  // ---- x fp32 -> bf16
    int i = blk*256 + tid;
    const float4_t* p = (const float4_t*)x + (size_t)i*2;
    float4_t a = p[0], b = p[1];
    short8 o;
    o[0]=f2bf(a[0]); o[1]=f2bf(a[1]); o[2]=f2bf(a[2]); o[3]=f2bf(a[3]);
    o[4]=f2bf(b[0]); o[5]=f2bf(b[1]); o[6]=f2bf(b[2]); o[7]=f2bf(b[3]);
    *((short8*)xb + i) = o;
    return;
  }
  if (blk < 3072){                                  // ---- mask -> prescaled transposed-fragment tiles
    // maskP flat = qg*16384 + kvt*1024 + lane*16 + nf*4 + j
    //   value = mask[qg*16 + li][kvt*64 + nf*16 + lg*4 + j] * LOG2E - 17.3123405
    int gid = (blk-2048)*256 + tid;
    int nf  = gid & 3;
    int lane= (gid>>2) & 63;
    int kvt = (gid>>8) & 15;
    int qg  = gid>>12;
    int li = lane & 15, lg = lane >> 4;
    int row = qg*16 + li;
    int col = kvt*64 + nf*16 + lg*4;
    float4_t m = *(const float4_t*)(mask + (size_t)row*1024 + col);
    float4_t o;
    #pragma unroll
    for (int j=0;j<4;++j) o[j] = fmaf(m[j], LOG2E, -17.3123405f);
    ((float4_t*)maskP)[gid] = o;
    return;
  }
  // ---- W [512][N] fp32 -> WT [N][512] bf16 (both weights)
  int idx = blk - 3072;                             // [0,256)
  int bx = idx & 31, by = idx >> 5;
  const float* W; short* WT; int N, n0;
  if (bx < 24){ W = W0; WT = WT0; N = N3; n0 = bx*64; }
  else        { W = W1; WT = WT1; N = DM; n0 = (bx-24)*64; }
  int k0 = by*64;
  int r = tid >> 4, c4 = (tid & 15) * 4;
  #pragma unroll
  for (int it=0; it<4; ++it){
    int rr = r + it*16;
    float4_t v = *(const float4_t*)(W + (size_t)(k0+rr)*N + n0 + c4);
    t[rr][c4+0]=v[0]; t[rr][c4+1]=v[1]; t[rr][c4+2]=v[2]; t[rr][c4+3]=v[3];
  }
  __syncthreads();
  #pragma unroll
  for (int it=0; it<4; ++it){
    int n = r + it*16;
    ushort4_t o;
    o[0]=(unsigned short)f2bf(t[c4+0][n]);
    o[1]=(unsigned short)f2bf(t[c4+1][n]);
    o[2]=(unsigned short)f2bf(t[c4+2][n]);
    o[3]=(unsigned short)f2bf(t[c4+3][n]);
    *(ushort4_t*)(WT + (size_t)(n0+n)*DM + k0 + c4) = o;
  }
}

// ---------------- GEMM1: 128x192 tiles, XCD-local A-panels, gload_lds + XOR-4 swizzle ----------------
// grid 1D 512: id = (x&7) + 8*y + 64*(x>>3)  ->  all 8 y-blocks of an A-panel share one XCD (id&7)
__global__ __launch_bounds__(256) void k_gemm_qkv(
    const short* __restrict__ A, const short* __restrict__ Bt,
    const float* __restrict__ bias,
    short* __restrict__ Qo, short* __restrict__ Ko, short* __restrict__ VTo)
{
  __shared__ __align__(16) short As[2][128*32];
  __shared__ __align__(16) short Bs[2][192*32];
  const int id  = blockIdx.x;
  const int xlo = id & 7, yy = (id>>3) & 7, xhi = id >> 6;
  const int m0  = (xhi*8 + xlo)*128, n0 = yy*192;
  const int tid = threadIdx.x;
  const int w = tid>>6, lane = tid&63, li = lane&15, lg = lane>>4;
  const int wr = (w>>1)*64, wc = (w&1)*96;

  // staging: chunk c -> lds row c>>2, lds slot c&3; global slot = (c&3)^(row&3)
  const int r0 = tid>>2;
  const int s0 = (tid&3) ^ (r0&3);       // rows +64/+128: row&3 identical -> same s0
  const int swz = li&3;                  // read-side xor

  #define G1_STAGE(buf, kt) do { \
    GLL(A  + (size_t)(m0+r0    )*DM + (kt)*32 + s0*8, &As[buf][tid*8]); \
    GLL(A  + (size_t)(m0+r0+64 )*DM + (kt)*32 + s0*8, &As[buf][(tid+256)*8]); \
    GLL(Bt + (size_t)(n0+r0    )*DM + (kt)*32 + s0*8, &Bs[buf][tid*8]); \
    GLL(Bt + (size_t)(n0+r0+64 )*DM + (kt)*32 + s0*8, &Bs[buf][(tid+256)*8]); \
    GLL(Bt + (size_t)(n0+r0+128)*DM + (kt)*32 + s0*8, &Bs[buf][(tid+512)*8]); \
  } while(0)

  const f32x4 fz = {0.f,0.f,0.f,0.f};
  f32x4 acc[4][6];
  #pragma unroll
  for (int i=0;i<4;++i)
    #pragma unroll
    for (int j=0;j<6;++j) acc[i][j] = fz;

  G1_STAGE(0, 0);
  __syncthreads();

  for (int kt=0; kt<16; ++kt){
    const short* as = As[kt&1]; const short* bs = Bs[kt&1];
    if (kt < 15) G1_STAGE((kt&1)^1, kt+1);
    short8 bfr[6];
    #pragma unroll
    for (int nf=0;nf<6;++nf)
      bfr[nf] = *(const short8*)&bs[(wc + nf*16 + li)*32 + (lg^swz)*8];
    __builtin_amdgcn_s_setprio(1);
    #pragma unroll
    for (int mf=0;mf<4;++mf){
      short8 af = *(const short8*)&as[(wr + mf*16 + li)*32 + (lg^swz)*8];
      #pragma unroll
      for (int nf=0;nf<6;++nf)
        acc[mf][nf] = MFMA16(af, bfr[nf], acc[mf][nf]);
    }
    __builtin_amdgcn_s_setprio(0);
    __syncthreads();
  }

  // epilogue: col n -> head h = n/192; within: [0,64)=Q, [64,128)=K, [128,192)=V(transposed store)
  #pragma unroll
  for (int nf=0;nf<6;++nf){
    int n = n0 + wc + nf*16 + li;
    float bv = bias[n];
    unsigned h  = (unsigned)n / 192u;
    unsigned wn = (unsigned)n % 192u;
    unsigned typ = wn >> 6, d = wn & 63u;
    #pragma unroll
    for (int mf=0;mf<4;++mf){
      #pragma unroll
      for (int j=0;j<4;++j){
        int m  = m0 + wr + mf*16 + lg*4 + j;
        int b  = m >> 10, lp = m & 1023;
        size_t bh = (size_t)(b*8 + (int)h);
        float vf = acc[mf][nf][j] + bv;
        if (typ == 0)      Qo [(bh<<16) + ((size_t)lp<<6)  + d]  = f2bf_fast(vf * 0.18033688f); // 0.125*log2e
        else if (typ == 1) Ko [(bh<<16) + ((size_t)lp<<6)  + d]  = f2bf_fast(vf);
        else               VTo[(bh<<16) + ((size_t)d<<10)  + lp] = f2bf_fast(vf);
      }
    }
  }
  #undef G1_STAGE
}

// ---------------- flash attention (proven): gload_lds K/V + XOR swizzle + XCD-local, P via LDS ----------------
__global__ __launch_bounds__(256, 2) void k_attn(
    const short* __restrict__ Q, const short* __restrict__ Kb,
    const short* __restrict__ VT, const float* __restrict__ maskP,
    short* __restrict__ O2)
{
  __shared__ __align__(16) short Ks[2][64*64];   // linear [kv][d], source-swizzled
  __shared__ __align__(16) short Vs[2][64*64];   // linear [d][kv], source-swizzled
  __shared__ __align__(16) short Ps[4][32*72];

  // XCD-local decode: all 8 q-blocks of a bh land on one XCD (hw xcd = id & 7)
  const int id  = blockIdx.x;
  const int bh  = (id & 7)*8 + ((id >> 3) & 7);
  const int q0  = (id >> 6) * 128;

  const int tid = threadIdx.x, w = tid>>6, lane = tid&63, li = lane&15, lg = lane>>4;
  const int qw = q0 + w*32;

  const short* Qp = Q  + ((size_t)bh<<16);
  const short* Kp = Kb + ((size_t)bh<<16);
  const short* Vp = VT + ((size_t)bh<<16);

  // staging chunk geometry: chunk c covers (row=c>>3, lds slot=c&7); global slot = lds slot ^ (row&7)
  const int arow0 = tid>>3;
  const int ags0  = (tid&7) ^ (arow0&7);         // chunk1: row+32 -> same (row&7), same gslot

  #define ATTN_STAGE(buf, nx) do { \
    GLL(Kp + ((size_t)((nx)+arow0   )<<6) + ags0*8, &Ks[buf][tid*8]); \
    GLL(Kp + ((size_t)((nx)+arow0+32)<<6) + ags0*8, &Ks[buf][(tid+256)*8]); \
    GLL(Vp + ((size_t)(arow0   )<<10) + (nx) + ags0*8, &Vs[buf][tid*8]); \
    GLL(Vp + ((size_t)(arow0+32)<<10) + (nx) + ags0*8, &Vs[buf][(tid+256)*8]); \
  } while(0)

  // Q as B-operand (col=q=li, k=d), two m-blocks; Q pre-scaled in GEMM1
  short8 qf[2][2];
  #pragma unroll
  for (int mb=0;mb<2;++mb)
    #pragma unroll
    for (int t=0;t<2;++t)
      qf[mb][t] = *(const short8*)(Qp + ((size_t)(qw+mb*16+li)<<6) + t*32 + lg*8);

  short8 ones8;
  #pragma unroll
  for (int e=0;e<8;++e) ones8[e] = (short)0x3f80;   // bf16 1.0

  const f32x4 fz = {0.f,0.f,0.f,0.f};
  f32x4 o[2][4], osum[2];
  #pragma unroll
  for (int mb=0;mb<2;++mb){
    osum[mb] = fz;
    #pragma unroll
    for (int df=0;df<4;++df) o[mb][df] = fz;
  }

  // mask (transposed-fragment, prescaled); register prefetch one tile ahead
  const float* mpb[2];
  #pragma unroll
  for (int mb=0;mb<2;++mb)
    mpb[mb] = maskP + ((size_t)((qw>>4)+mb)<<14) + lane*16;
  f32x4 mnx[2][4];
  #pragma unroll
  for (int mb=0;mb<2;++mb)
    #pragma unroll
    for (int nf=0;nf<4;++nf)
      mnx[mb][nf] = *(const float4_t*)(mpb[mb] + nf*4);

  ATTN_STAGE(0, 0);
  __syncthreads();     // drains vmcnt -> tile 0 staged

  const int sw = li & 7;
  short* pw = Ps[w];

  for (int kvt=0; kvt<16; ++kvt){
    const short* ks = Ks[kvt&1];
    const short* vs = Vs[kvt&1];
    if (kvt < 15) ATTN_STAGE((kvt&1)^1, (kvt+1)*64);

    // swapped QK^T: S^T[kv][q] tiles; C-init = prefetched mask regs
    f32x4 s[2][4];
    __builtin_amdgcn_s_setprio(1);
    #pragma unroll
    for (int nf=0;nf<4;++nf){
      short8 kf0 = *(const short8*)&ks[(nf*16+li)*64 + ((  lg)^sw)*8];
      short8 kf1 = *(const short8*)&ks[(nf*16+li)*64 + ((4|lg)^sw)*8];
      #pragma unroll
      for (int mb=0;mb<2;++mb){
        s[mb][nf] = MFMA16(kf0, qf[mb][0], mnx[mb][nf]);
        s[mb][nf] = MFMA16(kf1, qf[mb][1], s[mb][nf]);
      }
    }
    __builtin_amdgcn_s_setprio(0);

    // prefetch next tile's mask (consumed next iteration)
    if (kvt < 15){
      #pragma unroll
      for (int mb=0;mb<2;++mb)
        #pragma unroll
        for (int nf=0;nf<4;++nf)
          mnx[mb][nf] = *(const float4_t*)(mpb[mb] + (kvt+1)*1024 + nf*4);
    }

    // p = exp2(s) -> packed bf16 pairs -> Ps[q][kv] (b64 writes)
    #pragma unroll
    for (int mb=0;mb<2;++mb){
      #pragma unroll
      for (int nf=0;nf<4;++nf){
        float e0 = __builtin_amdgcn_exp2f(s[mb][nf][0]);
        float e1 = __builtin_amdgcn_exp2f(s[mb][nf][1]);
        float e2 = __builtin_amdgcn_exp2f(s[mb][nf][2]);
        float e3 = __builtin_amdgcn_exp2f(s[mb][nf][3]);
        unsigned p01, p23;
        asm("v_cvt_pk_bf16_f32 %0, %1, %2" : "=v"(p01) : "v"(e0), "v"(e1));
        asm("v_cvt_pk_bf16_f32 %0, %1, %2" : "=v"(p23) : "v"(e2), "v"(e3));
        u32x2 pv; pv[0]=p01; pv[1]=p23;
        *(u32x2*)&pw[(mb*16+li)*72 + nf*16 + lg*4] = pv;
      }
    }

    // PV: O[32q x 64d] += P @ V ; V-frags shared across both m-blocks
    __builtin_amdgcn_s_setprio(1);
    #pragma unroll
    for (int t=0;t<2;++t){
      short8 pf0 = *(const short8*)&pw[(   li)*72 + t*32 + lg*8];
      short8 pf1 = *(const short8*)&pw[(16+li)*72 + t*32 + lg*8];
      osum[0] = MFMA16(pf0, ones8, osum[0]);
      osum[1] = MFMA16(pf1, ones8, osum[1]);
      #pragma unroll
      for (int df=0;df<4;++df){
        short8 vf = *(const short8*)&vs[(df*16+li)*64 + (((t<<2)|lg)^sw)*8];
        o[0][df] = MFMA16(pf0, vf, o[0][df]);
        o[1][df] = MFMA16(pf1, vf, o[1][df]);
      }
    }
    __builtin_amdgcn_s_setprio(0);

    __syncthreads();   // buf[cur] reads done + buf[cur^1] DMA drained (vmcnt 0 at barrier)
  }
  #undef ATTN_STAGE

  // epilogue: O2[b, l, h*64+d] bf16
  int b = bh >> 3, h = bh & 7;
  #pragma unroll
  for (int mb=0;mb<2;++mb){
    float rl[4];
    #pragma unroll
    for (int j=0;j<4;++j) rl[j] = 1.0f / osum[mb][j];
    #pragma unroll
    for (int df=0;df<4;++df)
      #pragma unroll
      for (int j=0;j<4;++j){
        int m   = b*1024 + qw + mb*16 + lg*4 + j;
        int col = h*64 + df*16 + li;
        O2[(size_t)m*512 + col] = f2bf_fast(o[mb][df][j] * rl[j]);
      }
  }
}

// ---------------- GEMM2: 64x128 tiles, XCD-local A-panels, gload_lds + XOR-4 swizzle ----------------
// grid 1D 512: id = (x&7) + 8*y + 32*(x>>3) ; x in [0,128), y in [0,4)
__global__ __launch_bounds__(256) void k_gemm_out(
    const short* __restrict__ A, const short* __restrict__ Bt,
    const float* __restrict__ bias, float* __restrict__ out)
{
  __shared__ __align__(16) short As[2][64*32];
  __shared__ __align__(16) short Bs[2][128*32];
  const int id  = blockIdx.x;
  const int xlo = id & 7, yy = (id>>3) & 3, xhi = id >> 5;
  const int m0  = (xhi*8 + xlo)*64, n0 = yy*128;
  const int tid = threadIdx.x;
  const int w = tid>>6, lane = tid&63, li = lane&15, lg = lane>>4;
  const int wc = w*32;                  // wave covers cols [wc, wc+32), all 64 rows

  const int r0 = tid>>2;
  const int s0 = (tid&3) ^ (r0&3);
  const int swz = li&3;
  const int ra = tid>>2;                // A: 64 rows x 4 slots = 256 chunks (1 GLL)

  #define G2_STAGE(buf, kt) do { \
    GLL(A  + (size_t)(m0+ra    )*DM + (kt)*32 + s0*8, &As[buf][tid*8]); \
    GLL(Bt + (size_t)(n0+r0    )*DM + (kt)*32 + s0*8, &Bs[buf][tid*8]); \
    GLL(Bt + (size_t)(n0+r0+64 )*DM + (kt)*32 + s0*8, &Bs[buf][(tid+256)*8]); \
  } while(0)

  const f32x4 fz = {0.f,0.f,0.f,0.f};
  f32x4 acc[4][2];
  #pragma unroll
  for (int i=0;i<4;++i)
    #pragma unroll
    for (int j=0;j<2;++j) acc[i][j] = fz;

  G2_STAGE(0, 0);
  __syncthreads();

  for (int kt=0; kt<16; ++kt){
    const short* as = As[kt&1]; const short* bs = Bs[kt&1];
    if (kt < 15) G2_STAGE((kt&1)^1, kt+1);
    short8 bfr[2];
    #pragma unroll
    for (int nf=0;nf<2;++nf)
      bfr[nf] = *(const short8*)&bs[(wc + nf*16 + li)*32 + (lg^swz)*8];
    __builtin_amdgcn_s_setprio(1);
    #pragma unroll
    for (int mf=0;mf<4;++mf){
      short8 af = *(const short8*)&as[(mf*16 + li)*32 + (lg^swz)*8];
      #pragma unroll
      for (int nf=0;nf<2;++nf)
        acc[mf][nf] = MFMA16(af, bfr[nf], acc[mf][nf]);
    }
    __builtin_amdgcn_s_setprio(0);
    __syncthreads();
  }

  #pragma unroll
  for (int nf=0;nf<2;++nf){
    int n = n0 + wc + nf*16 + li;
    float bv = bias[n];
    #pragma unroll
    for (int mf=0;mf<4;++mf){
      #pragma unroll
      for (int j=0;j<4;++j){
        int m = m0 + mf*16 + lg*4 + j;
        out[(size_t)m*DM + n] = acc[mf][nf][j] + bv;
      }
    }
  }
  #undef G2_STAGE
}

extern "C" void kernel_launch(void* const* d_in, const int* in_sizes, int n_in,
                              void* d_out, int out_size, void* d_ws, size_t ws_size,
                              hipStream_t stream)
{
  (void)in_sizes; (void)n_in; (void)out_size; (void)ws_size;
  const float* x    = (const float*)d_in[0];
  const float* mask = (const float*)d_in[1];
  const float* Wqkv = (const float*)d_in[2];
  const float* bqkv = (const float*)d_in[3];
  const float* Wo   = (const float*)d_in[4];
  const float* bo   = (const float*)d_in[5];
  float* out = (float*)d_out;

  short* xb    = (short*)d_ws;                    // [8192,512] bf16
  short* WqkvT = xb    + (size_t)M_T*DM;          // [1536,512] bf16
  short* WoT   = WqkvT + (size_t)N3*DM;           // [512,512]  bf16
  short* Qb    = WoT   + (size_t)DM*DM;           // [64][1024][64] bf16 (pre-scaled)
  short* Kbf   = Qb    + (size_t)64*1024*64;      // [64][1024][64] bf16
  short* VTb   = Kbf   + (size_t)64*1024*64;      // [64][64][1024] bf16 (V^T)
  short* O2    = VTb   + (size_t)64*1024*64;      // [8192,512] bf16
  float* maskP = (float*)(O2 + (size_t)M_T*DM);   // [1024,1024] fp32 prescaled tiles (ws ~268MB, fits)

  k_prep<<<3328, 256, 0, stream>>>(x, xb, mask, maskP, Wqkv, WqkvT, Wo, WoT);
  k_gemm_qkv<<<512, 256, 0, stream>>>(xb, WqkvT, bqkv, Qb, Kbf, VTb);
  k_attn    <<<512, 256, 0, stream>>>(Qb, Kbf, VTb, maskP, O2);
  k_gemm_out<<<512, 256, 0, stream>>>(O2, WoT, bo, out);
}